// Round 14
// baseline (240.193 us; speedup 1.0000x reference)
//
#include <hip/hip_runtime.h>
#include <hip/hip_bf16.h>

// Problem constants (fixed by reference)
#define B_  4
#define E_  100000
#define N_  10000
#define NR_ 6
#define H_  256
#define D_  256
#define OUT_ 128
#define MAXDEG 48

typedef __attribute__((ext_vector_type(4))) float f32x4;
typedef __attribute__((ext_vector_type(8))) short bf16x8;

__device__ __forceinline__ ushort f2bf(float f) {
  unsigned u = __builtin_bit_cast(unsigned, f);
  u += 0x7fffu + ((u >> 16) & 1u);  // round-to-nearest-even
  return (ushort)(u >> 16);
}

__device__ __forceinline__ float bf2f(ushort u) {
  return __builtin_bit_cast(float, (unsigned)u << 16);
}

// ---------------------------------------------------------------------------
// Preamble: fixed-stride bucket fill (blocks 0..390) + weight packing
// (blocks 391..534). slot = atomicAdd(cnt[node]) -> buckets[node*MAXDEG+slot].
// Insertion order is nondeterministic; downstream is robust (hi/lo agg).
// Weight packing: f32 [K][C] -> bf16 MFMA B-fragment order
//   Wp[l][nb][ks][lane][8], elem = W_l[ks*32+(lane>>4)*8+j][nb*16+(lane&15)]
// ---------------------------------------------------------------------------
__global__ __launch_bounds__(256) void fill_convert_kernel(
    const int* __restrict__ idx, int* __restrict__ cnt,
    int* __restrict__ buckets, const float* __restrict__ W_up,
    const float* __restrict__ Ws, const float* __restrict__ W_out,
    ushort* __restrict__ Wp) {
  if (blockIdx.x < 391) {
    const int e = blockIdx.x * 256 + threadIdx.x;
    if (e < E_) {
      const int node = idx[e];
      const int pos = atomicAdd(&cnt[node], 1);
      if (pos < MAXDEG) buckets[node * MAXDEG + pos] = e;
    }
    return;
  }
  const int g = (blockIdx.x - 391) * 256 + threadIdx.x;  // < 36864
  int l, goff, Ncols;
  if (g < 32768) { l = g >> 13; goff = g & 8191; Ncols = 256; }
  else           { l = 4;       goff = g - 32768; Ncols = 128; }
  const float* src = (l == 0) ? W_up : (l < 4 ? Ws + (l - 1) * 65536 : W_out);
  const int lane = goff & 63;
  const int ks   = (goff >> 6) & 7;
  const int nb   = goff >> 9;
  const int col  = nb * 16 + (lane & 15);
  const int k0   = ks * 32 + (lane >> 4) * 8;
  ushort tmp[8];
#pragma unroll
  for (int j = 0; j < 8; ++j)
    tmp[j] = f2bf(src[(size_t)(k0 + j) * Ncols + col]);
  *reinterpret_cast<uint4*>(&Wp[(size_t)g * 8]) =
      *reinterpret_cast<const uint4*>(tmp);
}

// ---------------------------------------------------------------------------
// Mega-kernel: block = 16 nodes (64 act rows), 512 thr, ONE 32 KB act tile
// -> >=3 blocks/CU -> all 625 blocks co-resident (no tail round).
// Gather: wave owns 2 nodes; rp once/edge, 4 independent nontemporal 1KB
// x-loads. hi written to LDS; lo residual kept in 16 VGPRs.
// Layer 0 = two MFMA passes: hi@W, then (tile := lo from regs) lo@W into the
// same f32 accumulators -> agg enters layer 0 at ~f32 precision (R11 proof).
// Layers 1..4: standard single-tile bf16 path.
// ---------------------------------------------------------------------------
__global__ __launch_bounds__(512) void fused_kernel(
    const float* __restrict__ x, const float* __restrict__ rbf,
    const float* __restrict__ W_rbf, const int* __restrict__ cnt,
    const int* __restrict__ buckets, const ushort* __restrict__ Wp,
    const float* __restrict__ bs, float* __restrict__ out) {
  __shared__ ushort act[64 * 256];  // 32 KB
  char* actb = reinterpret_cast<char*>(act);
  const int n0 = blockIdx.x * 16;
  const int tid = threadIdx.x;
  const int wave = tid >> 6;
  const int lane = tid & 63;
  const int h0 = lane * 4;

  // ---- gather phase: 2 nodes per wave ----
  f32x4 wrv[NR_];
#pragma unroll
  for (int r = 0; r < NR_; ++r)
    wrv[r] = *reinterpret_cast<const f32x4*>(&W_rbf[r * H_ + h0]);

  ushort4 lo_keep[2][B_];  // 16 VGPRs: lo residuals survive until layer-0b
#pragma unroll
  for (int t = 0; t < 2; ++t) {
    const int nl = wave * 2 + t;
    const int node = n0 + nl;
    const int base = node * MAXDEG;
    const int d = min(cnt[node], MAXDEG);
    f32x4 acc[B_] = {};
#pragma unroll 2
    for (int j = 0; j < d; ++j) {
      const int e = buckets[base + j];
      f32x4 rp = {0.f, 0.f, 0.f, 0.f};
#pragma unroll
      for (int r = 0; r < NR_; ++r) rp += rbf[e * NR_ + r] * wrv[r];
#pragma unroll
      for (int b = 0; b < B_; ++b) {
        const f32x4 xv = __builtin_nontemporal_load(
            reinterpret_cast<const f32x4*>(&x[((size_t)b * E_ + e) * H_ + h0]));
        acc[b] += xv * rp;
      }
    }
#pragma unroll
    for (int b = 0; b < B_; ++b) {
      const int r = nl * 4 + b;  // tile row
      ushort4 oh, ol;
      oh.x = f2bf(acc[b].x); ol.x = f2bf(acc[b].x - bf2f(oh.x));
      oh.y = f2bf(acc[b].y); ol.y = f2bf(acc[b].y - bf2f(oh.y));
      oh.z = f2bf(acc[b].z); ol.z = f2bf(acc[b].z - bf2f(oh.z));
      oh.w = f2bf(acc[b].w); ol.w = f2bf(acc[b].w - bf2f(oh.w));
      const int byte = (r * 512 + h0 * 2) ^ ((r & 7) << 4);
      *reinterpret_cast<ushort4*>(actb + byte) = oh;
      lo_keep[t][b] = ol;
    }
  }
  __syncthreads();

  // ---- chain phase ----
  const int lr = lane & 15;
  const int lq = lane >> 4;
  const int wr = wave >> 2;  // 0..1 : 32-row strip
  const int wc = wave & 3;   // 0..3 : 64-col strip (32-col on final)

  // ---- layer 0: agg @ W_up, two-pass (hi then lo), no bias/act ----
  {
    const ushort* W = Wp;
    f32x4 acc[2][4] = {};
    // pass A: hi tile
#pragma unroll
    for (int ks = 0; ks < 8; ++ks) {
      bf16x8 af[2], bfr[4];
#pragma unroll
      for (int m = 0; m < 2; ++m) {
        const int row = wr * 32 + m * 16 + lr;
        const int byte = (row * 512 + ks * 64 + lq * 16) ^ ((row & 7) << 4);
        af[m] = *reinterpret_cast<const bf16x8*>(actb + byte);
      }
#pragma unroll
      for (int n = 0; n < 4; ++n) {
        const int nb = wc * 4 + n;
        bfr[n] = *reinterpret_cast<const bf16x8*>(
            &W[(size_t)(((nb * 8 + ks) * 64) + lane) * 8]);
      }
#pragma unroll
      for (int m = 0; m < 2; ++m)
#pragma unroll
        for (int n = 0; n < 4; ++n)
          acc[m][n] = __builtin_amdgcn_mfma_f32_16x16x32_bf16(af[m], bfr[n],
                                                              acc[m][n], 0, 0, 0);
    }
    __syncthreads();  // all waves done reading hi

    // overwrite tile with lo residuals (same lane-owned positions)
#pragma unroll
    for (int t = 0; t < 2; ++t) {
#pragma unroll
      for (int b = 0; b < B_; ++b) {
        const int r = (wave * 2 + t) * 4 + b;
        const int byte = (r * 512 + h0 * 2) ^ ((r & 7) << 4);
        *reinterpret_cast<ushort4*>(actb + byte) = lo_keep[t][b];
      }
    }
    __syncthreads();

    // pass B: lo tile, same accumulators
#pragma unroll
    for (int ks = 0; ks < 8; ++ks) {
      bf16x8 af[2], bfr[4];
#pragma unroll
      for (int m = 0; m < 2; ++m) {
        const int row = wr * 32 + m * 16 + lr;
        const int byte = (row * 512 + ks * 64 + lq * 16) ^ ((row & 7) << 4);
        af[m] = *reinterpret_cast<const bf16x8*>(actb + byte);
      }
#pragma unroll
      for (int n = 0; n < 4; ++n) {
        const int nb = wc * 4 + n;
        bfr[n] = *reinterpret_cast<const bf16x8*>(
            &W[(size_t)(((nb * 8 + ks) * 64) + lane) * 8]);
      }
#pragma unroll
      for (int m = 0; m < 2; ++m)
#pragma unroll
        for (int n = 0; n < 4; ++n)
          acc[m][n] = __builtin_amdgcn_mfma_f32_16x16x32_bf16(af[m], bfr[n],
                                                              acc[m][n], 0, 0, 0);
    }
    __syncthreads();  // all waves done reading lo

    // epilogue: write layer-0 output (no bias/act) into act tile
#pragma unroll
    for (int n = 0; n < 4; ++n) {
      const int col = wc * 64 + n * 16 + lr;
#pragma unroll
      for (int m = 0; m < 2; ++m) {
#pragma unroll
        for (int r = 0; r < 4; ++r) {
          const int row = wr * 32 + m * 16 + lq * 4 + r;
          const int byte = (row * 512 + col * 2) ^ ((row & 7) << 4);
          *reinterpret_cast<ushort*>(actb + byte) = f2bf(acc[m][n][r]);
        }
      }
    }
    __syncthreads();
  }

  // ---- layers 1..3: silu(h @ Ws[l-1] + bs[l-1]) ----
  for (int l = 1; l < 4; ++l) {
    const ushort* W = Wp + l * 65536;
    f32x4 acc[2][4] = {};
#pragma unroll
    for (int ks = 0; ks < 8; ++ks) {
      bf16x8 af[2], bfr[4];
#pragma unroll
      for (int m = 0; m < 2; ++m) {
        const int row = wr * 32 + m * 16 + lr;
        const int byte = (row * 512 + ks * 64 + lq * 16) ^ ((row & 7) << 4);
        af[m] = *reinterpret_cast<const bf16x8*>(actb + byte);
      }
#pragma unroll
      for (int n = 0; n < 4; ++n) {
        const int nb = wc * 4 + n;
        bfr[n] = *reinterpret_cast<const bf16x8*>(
            &W[(size_t)(((nb * 8 + ks) * 64) + lane) * 8]);
      }
#pragma unroll
      for (int m = 0; m < 2; ++m)
#pragma unroll
        for (int n = 0; n < 4; ++n)
          acc[m][n] = __builtin_amdgcn_mfma_f32_16x16x32_bf16(af[m], bfr[n],
                                                              acc[m][n], 0, 0, 0);
    }
    __syncthreads();  // all waves done READING act for this layer

#pragma unroll
    for (int n = 0; n < 4; ++n) {
      const int col = wc * 64 + n * 16 + lr;
      const float bv = bs[(l - 1) * 256 + col];
#pragma unroll
      for (int m = 0; m < 2; ++m) {
#pragma unroll
        for (int r = 0; r < 4; ++r) {
          float v = acc[m][n][r] + bv;
          v = v / (1.0f + __expf(-v));  // SiLU
          const int row = wr * 32 + m * 16 + lq * 4 + r;
          const int byte = (row * 512 + col * 2) ^ ((row & 7) << 4);
          *reinterpret_cast<ushort*>(actb + byte) = f2bf(v);
        }
      }
    }
    __syncthreads();  // writes visible before next layer reads
  }

  // final layer: 256 -> 128, f32 output. Tile row r -> out row (r&3)*N + n0 + (r>>2)
  {
    const ushort* W = Wp + 4 * 65536;
    f32x4 acc[2][2] = {};
#pragma unroll
    for (int ks = 0; ks < 8; ++ks) {
      bf16x8 af[2], bfr[2];
#pragma unroll
      for (int m = 0; m < 2; ++m) {
        const int row = wr * 32 + m * 16 + lr;
        const int byte = (row * 512 + ks * 64 + lq * 16) ^ ((row & 7) << 4);
        af[m] = *reinterpret_cast<const bf16x8*>(actb + byte);
      }
#pragma unroll
      for (int n = 0; n < 2; ++n) {
        const int nb = wc * 2 + n;
        bfr[n] = *reinterpret_cast<const bf16x8*>(
            &W[(size_t)(((nb * 8 + ks) * 64) + lane) * 8]);
      }
#pragma unroll
      for (int m = 0; m < 2; ++m)
#pragma unroll
        for (int n = 0; n < 2; ++n)
          acc[m][n] = __builtin_amdgcn_mfma_f32_16x16x32_bf16(af[m], bfr[n],
                                                              acc[m][n], 0, 0, 0);
    }
#pragma unroll
    for (int m = 0; m < 2; ++m)
#pragma unroll
      for (int n = 0; n < 2; ++n)
#pragma unroll
        for (int r = 0; r < 4; ++r) {
          const int rt = wr * 32 + m * 16 + lq * 4 + r;   // tile row 0..63
          const int row = (rt & 3) * N_ + n0 + (rt >> 2);  // b*N + node
          const int col = wc * 32 + n * 16 + lr;
          out[(size_t)row * OUT_ + col] = acc[m][n][r];
        }
  }
}

// ---------------------------------------------------------------------------
extern "C" void kernel_launch(void* const* d_in, const int* in_sizes, int n_in,
                              void* d_out, int out_size, void* d_ws,
                              size_t ws_size, hipStream_t stream) {
  const float* x     = (const float*)d_in[0];  // [B,E,H]
  const float* rbf   = (const float*)d_in[1];  // [E,NR]
  const int*   idx   = (const int*)d_in[2];    // [E]
  const float* W_rbf = (const float*)d_in[3];  // [NR,H]
  const float* W_up  = (const float*)d_in[4];  // [H,D]
  const float* Ws    = (const float*)d_in[5];  // [L,D,D]
  const float* bs    = (const float*)d_in[6];  // [L,D]
  const float* W_out = (const float*)d_in[7];  // [D,OUT]
  float* out = (float*)d_out;                  // [B,N,OUT] f32

  // workspace layout (bytes)
  char* ws = (char*)d_ws;
  ushort* Wp   = (ushort*)ws;                  // 589824 B
  int* cnt     = (int*)(ws + 589824);          // 40000 B
  int* buckets = (int*)(ws + 589824 + 40000);  // 10000*48*4 B

  // preamble: zero cnt, then single fill + weight-pack dispatch
  hipMemsetAsync(cnt, 0, N_ * sizeof(int), stream);
  fill_convert_kernel<<<391 + 144, 256, 0, stream>>>(idx, cnt, buckets, W_up,
                                                     Ws, W_out, Wp);

  // fused gather + 5-layer chain, 10000/16 = 625 node-tiles
  fused_kernel<<<625, 512, 0, stream>>>(x, rbf, W_rbf, cnt, buckets, Wp, bs,
                                        out);
}

// Round 16
// 162.199 us; speedup vs baseline: 1.4809x; 1.4809x over previous
//
#include <hip/hip_runtime.h>
#include <hip/hip_bf16.h>

// Problem constants (fixed by reference)
#define B_  4
#define E_  100000
#define N_  10000
#define NR_ 6
#define H_  256
#define D_  256
#define OUT_ 128
#define MAXDEG 48

typedef __attribute__((ext_vector_type(4))) float f32x4;
typedef __attribute__((ext_vector_type(8))) short bf16x8;

__device__ __forceinline__ ushort f2bf(float f) {
  unsigned u = __builtin_bit_cast(unsigned, f);
  u += 0x7fffu + ((u >> 16) & 1u);  // round-to-nearest-even
  return (ushort)(u >> 16);
}

__device__ __forceinline__ float bf2f(ushort u) {
  return __builtin_bit_cast(float, (unsigned)u << 16);
}

// ---------------------------------------------------------------------------
// Preamble: fixed-stride bucket fill (blocks 0..390) + weight packing
// (blocks 391..534). slot = atomicAdd(cnt[node]) -> buckets[node*MAXDEG+slot].
// Insertion order is nondeterministic; downstream is robust (hi/lo agg).
// Weight packing: f32 [K][C] -> bf16 MFMA B-fragment order
//   Wp[l][nb][ks][lane][8], elem = W_l[ks*32+(lane>>4)*8+j][nb*16+(lane&15)]
// ---------------------------------------------------------------------------
__global__ __launch_bounds__(256) void fill_convert_kernel(
    const int* __restrict__ idx, int* __restrict__ cnt,
    int* __restrict__ buckets, const float* __restrict__ W_up,
    const float* __restrict__ Ws, const float* __restrict__ W_out,
    ushort* __restrict__ Wp) {
  if (blockIdx.x < 391) {
    const int e = blockIdx.x * 256 + threadIdx.x;
    if (e < E_) {
      const int node = idx[e];
      const int pos = atomicAdd(&cnt[node], 1);
      if (pos < MAXDEG) buckets[node * MAXDEG + pos] = e;
    }
    return;
  }
  const int g = (blockIdx.x - 391) * 256 + threadIdx.x;  // < 36864
  int l, goff, Ncols;
  if (g < 32768) { l = g >> 13; goff = g & 8191; Ncols = 256; }
  else           { l = 4;       goff = g - 32768; Ncols = 128; }
  const float* src = (l == 0) ? W_up : (l < 4 ? Ws + (l - 1) * 65536 : W_out);
  const int lane = goff & 63;
  const int ks   = (goff >> 6) & 7;
  const int nb   = goff >> 9;
  const int col  = nb * 16 + (lane & 15);
  const int k0   = ks * 32 + (lane >> 4) * 8;
  ushort tmp[8];
#pragma unroll
  for (int j = 0; j < 8; ++j)
    tmp[j] = f2bf(src[(size_t)(k0 + j) * Ncols + col]);
  *reinterpret_cast<uint4*>(&Wp[(size_t)g * 8]) =
      *reinterpret_cast<const uint4*>(tmp);
}

// ---------------------------------------------------------------------------
// Mega-kernel (R12 structure, proven): block = 16 nodes (64 act rows),
// 512 thr (8 waves), dual 32 KB hi/lo swizzled LDS tiles. NO launch_bounds
// min-wave clamp (R13/R14 lesson: MFMA kernels must not be register-starved).
// Gather: wave owns 2 nodes; rp once/edge, 4 independent nontemporal 1KB
// x-loads. hi -> actH, lo residual -> actL.
// Layer 0 = hi@W + lo@W (agg enters at ~f32 precision); layers 1..4 bf16.
// s_setprio(1) wraps MFMA clusters: chain-phase waves win issue arbitration
// over gather-phase waves of the co-resident block (T5 mechanism).
// ---------------------------------------------------------------------------
__global__ __launch_bounds__(512) void fused_kernel(
    const float* __restrict__ x, const float* __restrict__ rbf,
    const float* __restrict__ W_rbf, const int* __restrict__ cnt,
    const int* __restrict__ buckets, const ushort* __restrict__ Wp,
    const float* __restrict__ bs, float* __restrict__ out) {
  __shared__ ushort actH[64 * 256];  // 32 KB (hi tile; layers 1+ act tile)
  __shared__ ushort actL[64 * 256];  // 32 KB (lo tile; layer-0 only)
  char* actb = reinterpret_cast<char*>(actH);
  char* actlb = reinterpret_cast<char*>(actL);
  const int n0 = blockIdx.x * 16;
  const int tid = threadIdx.x;
  const int wave = tid >> 6;
  const int lane = tid & 63;
  const int h0 = lane * 4;

  // ---- gather phase: 2 nodes per wave ----
  f32x4 wrv[NR_];
#pragma unroll
  for (int r = 0; r < NR_; ++r)
    wrv[r] = *reinterpret_cast<const f32x4*>(&W_rbf[r * H_ + h0]);

#pragma unroll
  for (int t = 0; t < 2; ++t) {
    const int nl = wave * 2 + t;
    const int node = n0 + nl;
    const int base = node * MAXDEG;
    const int d = min(cnt[node], MAXDEG);
    f32x4 acc[B_] = {};
#pragma unroll 2
    for (int j = 0; j < d; ++j) {
      const int e = buckets[base + j];
      f32x4 rp = {0.f, 0.f, 0.f, 0.f};
#pragma unroll
      for (int r = 0; r < NR_; ++r) rp += rbf[e * NR_ + r] * wrv[r];
#pragma unroll
      for (int b = 0; b < B_; ++b) {
        const f32x4 xv = __builtin_nontemporal_load(
            reinterpret_cast<const f32x4*>(&x[((size_t)b * E_ + e) * H_ + h0]));
        acc[b] += xv * rp;
      }
    }
#pragma unroll
    for (int b = 0; b < B_; ++b) {
      const int r = nl * 4 + b;  // tile row
      // hi/lo bf16 decomposition: hi + lo ~= f32 value (rel err ~2^-16)
      ushort4 oh, ol;
      oh.x = f2bf(acc[b].x); ol.x = f2bf(acc[b].x - bf2f(oh.x));
      oh.y = f2bf(acc[b].y); ol.y = f2bf(acc[b].y - bf2f(oh.y));
      oh.z = f2bf(acc[b].z); ol.z = f2bf(acc[b].z - bf2f(oh.z));
      oh.w = f2bf(acc[b].w); ol.w = f2bf(acc[b].w - bf2f(oh.w));
      const int byte = (r * 512 + h0 * 2) ^ ((r & 7) << 4);
      *reinterpret_cast<ushort4*>(actb + byte) = oh;
      *reinterpret_cast<ushort4*>(actlb + byte) = ol;
    }
  }
  __syncthreads();

  // ---- chain phase ----
  const int lr = lane & 15;
  const int lq = lane >> 4;
  const int wr = wave >> 2;  // 0..1 : 32-row strip
  const int wc = wave & 3;   // 0..3 : 64-col strip (32-col on final)

  for (int l = 0; l < 4; ++l) {
    const ushort* W = Wp + l * 65536;
    f32x4 acc[2][4] = {};
    __builtin_amdgcn_s_setprio(1);
#pragma unroll
    for (int ks = 0; ks < 8; ++ks) {
      bf16x8 af[2], bfr[4];
#pragma unroll
      for (int m = 0; m < 2; ++m) {
        const int row = wr * 32 + m * 16 + lr;
        const int byte = (row * 512 + ks * 64 + lq * 16) ^ ((row & 7) << 4);
        af[m] = *reinterpret_cast<const bf16x8*>(actb + byte);
      }
#pragma unroll
      for (int n = 0; n < 4; ++n) {
        const int nb = wc * 4 + n;
        bfr[n] = *reinterpret_cast<const bf16x8*>(
            &W[(size_t)(((nb * 8 + ks) * 64) + lane) * 8]);
      }
#pragma unroll
      for (int m = 0; m < 2; ++m)
#pragma unroll
        for (int n = 0; n < 4; ++n)
          acc[m][n] = __builtin_amdgcn_mfma_f32_16x16x32_bf16(af[m], bfr[n],
                                                              acc[m][n], 0, 0, 0);
      if (l == 0) {
        // lo-tile contribution: layer 0 only -> A ~= f32-exact agg
        bf16x8 afl[2];
#pragma unroll
        for (int m = 0; m < 2; ++m) {
          const int row = wr * 32 + m * 16 + lr;
          const int byte = (row * 512 + ks * 64 + lq * 16) ^ ((row & 7) << 4);
          afl[m] = *reinterpret_cast<const bf16x8*>(actlb + byte);
        }
#pragma unroll
        for (int m = 0; m < 2; ++m)
#pragma unroll
          for (int n = 0; n < 4; ++n)
            acc[m][n] = __builtin_amdgcn_mfma_f32_16x16x32_bf16(
                afl[m], bfr[n], acc[m][n], 0, 0, 0);
      }
    }
    __builtin_amdgcn_s_setprio(0);
    __syncthreads();  // all waves done READING act for this layer

    const bool ba = (l > 0);
#pragma unroll
    for (int n = 0; n < 4; ++n) {
      const int col = wc * 64 + n * 16 + lr;
      const float bv = ba ? bs[(l - 1) * 256 + col] : 0.f;
#pragma unroll
      for (int m = 0; m < 2; ++m) {
#pragma unroll
        for (int r = 0; r < 4; ++r) {
          float v = acc[m][n][r];
          if (ba) {
            v += bv;
            v = v / (1.0f + __expf(-v));  // SiLU
          }
          const int row = wr * 32 + m * 16 + lq * 4 + r;
          const int byte = (row * 512 + col * 2) ^ ((row & 7) << 4);
          *reinterpret_cast<ushort*>(actb + byte) = f2bf(v);
        }
      }
    }
    __syncthreads();  // writes visible before next layer reads
  }

  // final layer: 256 -> 128, f32 output. Tile row r -> out row (r&3)*N + n0 + (r>>2)
  {
    const ushort* W = Wp + 4 * 65536;
    f32x4 acc[2][2] = {};
    __builtin_amdgcn_s_setprio(1);
#pragma unroll
    for (int ks = 0; ks < 8; ++ks) {
      bf16x8 af[2], bfr[2];
#pragma unroll
      for (int m = 0; m < 2; ++m) {
        const int row = wr * 32 + m * 16 + lr;
        const int byte = (row * 512 + ks * 64 + lq * 16) ^ ((row & 7) << 4);
        af[m] = *reinterpret_cast<const bf16x8*>(actb + byte);
      }
#pragma unroll
      for (int n = 0; n < 2; ++n) {
        const int nb = wc * 2 + n;
        bfr[n] = *reinterpret_cast<const bf16x8*>(
            &W[(size_t)(((nb * 8 + ks) * 64) + lane) * 8]);
      }
#pragma unroll
      for (int m = 0; m < 2; ++m)
#pragma unroll
        for (int n = 0; n < 2; ++n)
          acc[m][n] = __builtin_amdgcn_mfma_f32_16x16x32_bf16(af[m], bfr[n],
                                                              acc[m][n], 0, 0, 0);
    }
    __builtin_amdgcn_s_setprio(0);
#pragma unroll
    for (int m = 0; m < 2; ++m)
#pragma unroll
      for (int n = 0; n < 2; ++n)
#pragma unroll
        for (int r = 0; r < 4; ++r) {
          const int rt = wr * 32 + m * 16 + lq * 4 + r;   // tile row 0..63
          const int row = (rt & 3) * N_ + n0 + (rt >> 2);  // b*N + node
          const int col = wc * 32 + n * 16 + lr;
          out[(size_t)row * OUT_ + col] = acc[m][n][r];
        }
  }
}

// ---------------------------------------------------------------------------
extern "C" void kernel_launch(void* const* d_in, const int* in_sizes, int n_in,
                              void* d_out, int out_size, void* d_ws,
                              size_t ws_size, hipStream_t stream) {
  const float* x     = (const float*)d_in[0];  // [B,E,H]
  const float* rbf   = (const float*)d_in[1];  // [E,NR]
  const int*   idx   = (const int*)d_in[2];    // [E]
  const float* W_rbf = (const float*)d_in[3];  // [NR,H]
  const float* W_up  = (const float*)d_in[4];  // [H,D]
  const float* Ws    = (const float*)d_in[5];  // [L,D,D]
  const float* bs    = (const float*)d_in[6];  // [L,D]
  const float* W_out = (const float*)d_in[7];  // [D,OUT]
  float* out = (float*)d_out;                  // [B,N,OUT] f32

  // workspace layout (bytes)
  char* ws = (char*)d_ws;
  ushort* Wp   = (ushort*)ws;                  // 589824 B
  int* cnt     = (int*)(ws + 589824);          // 40000 B
  int* buckets = (int*)(ws + 589824 + 40000);  // 10000*48*4 B

  // preamble: zero cnt, then single fill + weight-pack dispatch
  hipMemsetAsync(cnt, 0, N_ * sizeof(int), stream);
  fill_convert_kernel<<<391 + 144, 256, 0, stream>>>(idx, cnt, buckets, W_up,
                                                     Ws, W_out, Wp);

  // fused gather + 5-layer chain, 10000/16 = 625 node-tiles
  fused_kernel<<<625, 512, 0, stream>>>(x, rbf, W_rbf, cnt, buckets, Wp, bs,
                                        out);
}